// Round 19
// baseline (127.787 us; speedup 1.0000x reference)
//
#include <hip/hip_runtime.h>

#define N_TOK 16384
#define M_TOK 2048
#define NHEADS 8
#define DH 64
#define CIN 128
#define INNER 512

typedef __attribute__((ext_vector_type(8))) short bf16x8;
typedef __attribute__((ext_vector_type(16))) float f32x16;
typedef __attribute__((ext_vector_type(4))) unsigned int u32x4;
typedef __attribute__((ext_vector_type(2))) unsigned int u32x2;

// Softmax base: native exp2 (compiler-managed TRANS hazards); QS folds 0.125*log2(e)
// into Wqb so exp2(S) == exp(S/8). Single #if keeps base and scale consistent.
#if __has_builtin(__builtin_amdgcn_exp2f)
#define QS 0.18033688011112042f
#define EXPF(x) __builtin_amdgcn_exp2f(x)
#else
#define QS 0.125f
#define EXPF(x) __expf(x)
#endif

__device__ __forceinline__ unsigned short f2bf(float f) {
    unsigned u = __float_as_uint(f);
    u += 0x7fff + ((u >> 16) & 1);          // RNE
    return (unsigned short)(u >> 16);
}

__device__ __forceinline__ unsigned cvtpk(float lo, float hi) {
    unsigned r;
    asm("v_cvt_pk_bf16_f32 %0, %1, %2" : "=v"(r) : "v"(lo), "v"(hi));
    return r;
}

__device__ __forceinline__ bf16x8 mk_bf16x8(unsigned a, unsigned b, unsigned c, unsigned d) {
    union { u32x4 w; bf16x8 h; } u;
    u.w = (u32x4){a, b, c, d};
    return u.h;
}

__device__ __forceinline__ void gload16(const void* g, void* l) {
    __builtin_amdgcn_global_load_lds(
        (const __attribute__((address_space(1))) unsigned int*)g,
        (__attribute__((address_space(3))) unsigned int*)l, 16, 0, 0);
}

// ---------------- prep: wconv (0..63) + avg-pool (64..1087) + xT (1088..1343) ----------------
__global__ __launch_bounds__(256) void prep_k(const float* __restrict__ Wq,
                                              const float* __restrict__ Wo,
                                              const float* __restrict__ cin,
                                              const float* __restrict__ x,
                                              unsigned short* __restrict__ Wqb,
                                              unsigned short* __restrict__ Wob,
                                              float* __restrict__ cout,
                                              unsigned short* __restrict__ xb) {
    __shared__ unsigned short tile[64 * 132];
    const int t = threadIdx.x;
    if (blockIdx.x < 64) {
        int i = (blockIdx.x * 256 + t) * 8;
        const float* src; unsigned short* dst; float sc;
        if (i < 65536) { src = Wq + i; dst = Wqb + i; sc = QS; }
        else           { src = Wo + (i - 65536); dst = Wob + (i - 65536); sc = 1.0f; }
        float4 a = *reinterpret_cast<const float4*>(src);
        float4 b = *reinterpret_cast<const float4*>(src + 4);
        unsigned short u[8] = { f2bf(a.x * sc), f2bf(a.y * sc), f2bf(a.z * sc), f2bf(a.w * sc),
                                f2bf(b.x * sc), f2bf(b.y * sc), f2bf(b.z * sc), f2bf(b.w * sc) };
        *reinterpret_cast<uint4*>(dst) = *reinterpret_cast<uint4*>(u);
    } else if (blockIdx.x < 1088) {
        int idx = (blockIdx.x - 64) * 256 + t;
        int c = idx >> 11, m = idx & 2047;
        int d2 = m >> 8, h2 = (m >> 4) & 15, w2 = m & 15;
        const float* b = cin + c * 16384 + d2 * 2048 + h2 * 64 + w2 * 2;
        float s = b[0] + b[1] + b[32] + b[33] + b[1024] + b[1025] + b[1056] + b[1057];
        cout[idx] = s * 0.125f;
    } else {
        const int xbid = blockIdx.x - 1088;
        const int n0 = (xbid & 127) * 128;
        const int cb = (xbid >> 7) * 64;
#pragma unroll
        for (int cc2 = 0; cc2 < 2; ++cc2)
#pragma unroll
            for (int lp = 0; lp < 4; ++lp) {
                int id = lp * 256 + t;
                int row = id >> 5, ch = id & 31;
                float4 v = *reinterpret_cast<const float4*>(
                    &x[(size_t)(cb + cc2 * 32 + row) * N_TOK + n0 + ch * 4]);
                unsigned short u[4] = { f2bf(v.x), f2bf(v.y), f2bf(v.z), f2bf(v.w) };
                *reinterpret_cast<uint2*>(&tile[(cc2 * 32 + row) * 132 + ch * 4]) =
                    *reinterpret_cast<uint2*>(u);
            }
        __syncthreads();
#pragma unroll
        for (int lp = 0; lp < 4; ++lp) {
            int id = lp * 256 + t;
            int n = id >> 3, cg = id & 7;
            unsigned short u[8];
#pragma unroll
            for (int j = 0; j < 8; ++j) u[j] = tile[(cg * 8 + j) * 132 + n];
            *reinterpret_cast<uint4*>(&xb[(size_t)(n0 + n) * 128 + cb + cg * 8]) =
                *reinterpret_cast<uint4*>(u);
        }
    }
}

// ---------------- fused projections: kvproj (blocks 0..1023) + qproj (1024..1535) ----------------
__global__ __launch_bounds__(256) void projs_k(const float* __restrict__ ctx,
                                               const float* __restrict__ Wk,
                                               const float* __restrict__ Wv,
                                               const unsigned short* __restrict__ Wqb,
                                               const unsigned short* __restrict__ xb,
                                               unsigned short* __restrict__ Kb,
                                               unsigned short* __restrict__ Vb,
                                               unsigned short* __restrict__ Qb) {
    __shared__ __align__(16) char xls[8192];   // qproj: xb tile [32n][128c] bf16 swizzled
    const int b = blockIdx.x;
    const int t = threadIdx.x;
    if (b < 1024) {
        const int bx = b & 3, by = (b >> 2) & 127, bz = b >> 9;
        const int m0 = (bx * 256 + t) * 2;
        const int o0 = by * 4;
        const float* W = bz ? Wv : Wk;
        float acc[4][2];
#pragma unroll
        for (int j = 0; j < 4; ++j) { acc[j][0] = 0.f; acc[j][1] = 0.f; }
        for (int c4 = 0; c4 < CIN / 4; ++c4) {
            float xa[4][2];
#pragma unroll
            for (int cc = 0; cc < 4; ++cc)
                *reinterpret_cast<float2*>(xa[cc]) =
                    *reinterpret_cast<const float2*>(&ctx[(size_t)(c4 * 4 + cc) * M_TOK + m0]);
#pragma unroll
            for (int j = 0; j < 4; ++j) {
                float4 wv = *reinterpret_cast<const float4*>(&W[(o0 + j) * CIN + c4 * 4]);
#pragma unroll
                for (int k = 0; k < 2; ++k) {
                    acc[j][k] = fmaf(wv.x, xa[0][k], acc[j][k]);
                    acc[j][k] = fmaf(wv.y, xa[1][k], acc[j][k]);
                    acc[j][k] = fmaf(wv.z, xa[2][k], acc[j][k]);
                    acc[j][k] = fmaf(wv.w, xa[3][k], acc[j][k]);
                }
            }
        }
        if (bz) {
#pragma unroll
            for (int j = 0; j < 4; ++j) {
                unsigned w0 = (unsigned)f2bf(acc[j][0]) | ((unsigned)f2bf(acc[j][1]) << 16);
                *reinterpret_cast<unsigned*>(&Vb[(size_t)(o0 + j) * M_TOK + m0]) = w0;
            }
        } else {
            const int h = o0 >> 6, d0 = o0 & 63;
#pragma unroll
            for (int k = 0; k < 2; ++k) {
                unsigned short u[4];
#pragma unroll
                for (int j = 0; j < 4; ++j) u[j] = f2bf(acc[j][k]);
                *reinterpret_cast<uint2*>(&Kb[((size_t)h * M_TOK + m0 + k) * DH + d0]) =
                    *reinterpret_cast<uint2*>(u);
            }
        }
    } else {
        // ---- Q proj MFMA, xb tile staged through LDS (coalesced + swizzled) ----
        const int bid = b - 1024;
        const int w = t >> 6, l = t & 63;
        const int la = l & 31, lg = l >> 5;
        const int n0t = bid * 32;
#pragma unroll
        for (int i = 0; i < 2; ++i) {
            int c = i * 256 + t;
            int n = c >> 4, ch = (c & 15) * 16;
            uint4 v = *reinterpret_cast<const uint4*>(
                reinterpret_cast<const char*>(xb + (size_t)(n0t + n) * CIN) + ch);
            *reinterpret_cast<uint4*>(xls + n * 256 + (ch ^ ((n & 7) << 4))) = v;
        }
        __syncthreads();

        bf16x8 bx[8];
        const int xsw = (la & 7) << 4;
#pragma unroll
        for (int ks = 0; ks < 8; ++ks)
            bx[ks] = *reinterpret_cast<const bf16x8*>(
                xls + la * 256 + ((ks * 32 + lg * 16) ^ xsw));

        f32x16 acc[4];
#pragma unroll
        for (int os = 0; os < 4; ++os) acc[os] = (f32x16){0,0,0,0,0,0,0,0,0,0,0,0,0,0,0,0};

#pragma unroll
        for (int os = 0; os < 4; ++os) {
            const int row = w * 128 + os * 32 + la;
#pragma unroll
            for (int ks = 0; ks < 8; ++ks) {
                bf16x8 aw = *reinterpret_cast<const bf16x8*>(Wqb + (size_t)row * 128 + ks * 16 + lg * 8);
                acc[os] = __builtin_amdgcn_mfma_f32_32x32x16_bf16(aw, bx[ks], acc[os], 0, 0, 0);
            }
        }
        const int n = n0t + la;
#pragma unroll
        for (int os = 0; os < 4; ++os) {
            const int h = w * 2 + (os >> 1);
            const int dbase = (os & 1) * 32 + 4 * lg;
#pragma unroll
            for (int rr = 0; rr < 4; ++rr) {
                unsigned p0 = cvtpk(acc[os][rr * 4 + 0], acc[os][rr * 4 + 1]);
                unsigned p1 = cvtpk(acc[os][rr * 4 + 2], acc[os][rr * 4 + 3]);
                uint2 pv = make_uint2(p0, p1);
                *reinterpret_cast<uint2*>(&Qb[((size_t)h * N_TOK + n) * DH + dbase + rr * 8]) = pv;
            }
        }
    }
}

// ---------------- MFMA flash attention: 8 waves, 256 q-rows, m-tile 128, 2-deep phase pipeline ----
// grid 512: h = bid&7 (XCD-pinned), n0 = (bid>>3)*256. 2 blocks/CU.
// QK(ms+1) issued BEFORE exp/PV(ms): exp VALU overlaps QK MFMA execution (in-tile only —
// never across the barrier). Named rotation vars, static indexing (rule 20).
__global__ __launch_bounds__(512, 4) void attn_k(const unsigned short* __restrict__ Qb,
                                                 const unsigned short* __restrict__ Kb,
                                                 const unsigned short* __restrict__ Vb,
                                                 unsigned short* __restrict__ Ob) {
    __shared__ __align__(16) char smem[65536];   // 2 bufs x (K 16KB + V 16KB); epilogue Ot

    const int t = threadIdx.x;
    const int w = t >> 6, l = t & 63;
    const int la = l & 31, lg = l >> 5;
    const int bid = blockIdx.x;
    const int h = bid & 7;
    const int n0 = (bid >> 3) * 256;

    bf16x8 aq[4];
    {
        const unsigned short* qrow = Qb + ((size_t)h * N_TOK + n0 + w * 32 + la) * DH + lg * 8;
#pragma unroll
        for (int ks = 0; ks < 4; ++ks)
            aq[ks] = *reinterpret_cast<const bf16x8*>(qrow + ks * 16);
    }

    const bf16x8 vone = mk_bf16x8(0x3F803F80u, 0x3F803F80u, 0x3F803F80u, 0x3F803F80u);

    const char* gK = (const char*)Kb + (size_t)h * M_TOK * 128;   // K rows 128B
    const char* gV = (const char*)Vb + (size_t)h * DH * 4096;     // V rows 4096B

    // Index-based staging addresses only (loop-carried pointer chains spill: R11/R12).
    auto stage = [&](int b, int tile) {
        char* buf = smem + b * 32768;
#pragma unroll
        for (int i = 0; i < 2; ++i) {
            int c = t + i * 512;
            int row = c >> 3, o16 = (c & 7) << 4;
            gload16(gK + (size_t)(tile * 128 + row) * 128 + (o16 ^ ((row & 7) << 4)),
                    buf + c * 16);
            int vrow = c >> 4, vo16 = (c & 15) << 4;
            gload16(gV + (size_t)vrow * 4096 + tile * 256 + (vo16 ^ ((vrow & 7) << 4)),
                    buf + 16384 + c * 16);
        }
    };

    // QK phase: S^T tile for phase ms (lane holds P[n=la][m=ms*32+crow(r,lg)])
    auto qk = [&](int cb, int ms) -> f32x16 {
        f32x16 s = {0,0,0,0,0,0,0,0,0,0,0,0,0,0,0,0};
        const int row = ms * 32 + la;
        const int sw = (row & 7) << 4;
        __builtin_amdgcn_s_setprio(1);
#pragma unroll
        for (int ks = 0; ks < 4; ++ks) {
            bf16x8 ak = *reinterpret_cast<const bf16x8*>(
                smem + cb + row * 128 + ((32 * ks + 16 * lg) ^ sw));
            s = __builtin_amdgcn_mfma_f32_32x32x16_bf16(ak, aq[ks], s, 0, 0, 0);
        }
        __builtin_amdgcn_s_setprio(0);
        return s;
    };

    f32x16 oacc0 = {0,0,0,0,0,0,0,0,0,0,0,0,0,0,0,0};
    f32x16 oacc1 = {0,0,0,0,0,0,0,0,0,0,0,0,0,0,0,0};
    f32x16 oaccS = {0,0,0,0,0,0,0,0,0,0,0,0,0,0,0,0};   // rowsum via mfma(P, ones)

    // exp + repack + PV + rowsum for phase ms, consuming sacc
    auto finish = [&](int cb, int ms, const f32x16& sacc) {
        float p[16];
#pragma unroll
        for (int r = 0; r < 16; ++r) p[r] = EXPF(sacc[r]);
        u32x2 s0 = __builtin_amdgcn_permlane32_swap(cvtpk(p[0], p[1]),  cvtpk(p[4], p[5]),  false, false);
        u32x2 s1 = __builtin_amdgcn_permlane32_swap(cvtpk(p[2], p[3]),  cvtpk(p[6], p[7]),  false, false);
        u32x2 s2 = __builtin_amdgcn_permlane32_swap(cvtpk(p[8], p[9]),  cvtpk(p[12], p[13]), false, false);
        u32x2 s3 = __builtin_amdgcn_permlane32_swap(cvtpk(p[10], p[11]), cvtpk(p[14], p[15]), false, false);
        bf16x8 pa0 = mk_bf16x8(s0.x, s1.x, s0.y, s1.y);
        bf16x8 pa1 = mk_bf16x8(s2.x, s3.x, s2.y, s3.y);
        __builtin_amdgcn_s_setprio(1);
        oaccS = __builtin_amdgcn_mfma_f32_32x32x16_bf16(pa0, vone, oaccS, 0, 0, 0);
        oaccS = __builtin_amdgcn_mfma_f32_32x32x16_bf16(pa1, vone, oaccS, 0, 0, 0);
        {
            const int vrow = la, vs = (vrow & 7) << 4;
            const char* vb = smem + cb + 16384 + vrow * 256;
            bf16x8 bv0 = *reinterpret_cast<const bf16x8*>(vb + ((64 * ms + 16 * lg) ^ vs));
            bf16x8 bv1 = *reinterpret_cast<const bf16x8*>(vb + ((64 * ms + 32 + 16 * lg) ^ vs));
            oacc0 = __builtin_amdgcn_mfma_f32_32x32x16_bf16(pa0, bv0, oacc0, 0, 0, 0);
            oacc0 = __builtin_amdgcn_mfma_f32_32x32x16_bf16(pa1, bv1, oacc0, 0, 0, 0);
        }
        {
            const int vrow = 32 + la, vs = (vrow & 7) << 4;
            const char* vb = smem + cb + 16384 + vrow * 256;
            bf16x8 bv0 = *reinterpret_cast<const bf16x8*>(vb + ((64 * ms + 16 * lg) ^ vs));
            bf16x8 bv1 = *reinterpret_cast<const bf16x8*>(vb + ((64 * ms + 32 + 16 * lg) ^ vs));
            oacc1 = __builtin_amdgcn_mfma_f32_32x32x16_bf16(pa0, bv0, oacc1, 0, 0, 0);
            oacc1 = __builtin_amdgcn_mfma_f32_32x32x16_bf16(pa1, bv1, oacc1, 0, 0, 0);
        }
        __builtin_amdgcn_s_setprio(0);
    };

    stage(0, 0);
    __syncthreads();

#pragma unroll 2
    for (int mt = 0; mt < M_TOK / 128; ++mt) {
        const int cb = (mt & 1) * 32768;
        if (mt < M_TOK / 128 - 1) stage((mt & 1) ^ 1, mt + 1);

        // 2-deep rotation: QK(ms+1) issues before finish(ms) so exp overlaps MFMA exec
        f32x16 sA = qk(cb, 0);
        f32x16 sB = qk(cb, 1);
        finish(cb, 0, sA);
        sA = qk(cb, 2);
        finish(cb, 1, sB);
        sB = qk(cb, 3);
        finish(cb, 2, sA);
        finish(cb, 3, sB);

        __syncthreads();
    }

    float inv[16];
#pragma unroll
    for (int r = 0; r < 16; ++r) inv[r] = __builtin_amdgcn_rcpf(oaccS[r]);

    float* Ot = reinterpret_cast<float*>(smem);
#pragma unroll
    for (int pass = 0; pass < 2; ++pass) {
        __syncthreads();
        if ((w >> 2) == pass) {
            const int wl = w & 3;
#pragma unroll
            for (int dt = 0; dt < 2; ++dt)
#pragma unroll
                for (int r = 0; r < 16; r += 2) {
                    int d = dt * 32 + la;
                    int n = wl * 32 + (r & 3) + 8 * (r >> 2) + 4 * lg;
                    float2 v;
                    v.x = (dt ? oacc1[r] : oacc0[r]) * inv[r];
                    v.y = (dt ? oacc1[r + 1] : oacc0[r + 1]) * inv[r + 1];
                    *reinterpret_cast<float2*>(&Ot[d * 132 + n]) = v;
                }
        }
        __syncthreads();
#pragma unroll
        for (int i = 0; i < 2; ++i) {
            int id = i * 512 + t;
            int n = id & 127, dg = id >> 7;
            unsigned q[4];
#pragma unroll
            for (int jj = 0; jj < 4; ++jj)
                q[jj] = cvtpk(Ot[(dg * 8 + jj * 2) * 132 + n],
                              Ot[(dg * 8 + jj * 2 + 1) * 132 + n]);
            *reinterpret_cast<uint4*>(&Ob[(size_t)(n0 + pass * 128 + n) * INNER + h * 64 + dg * 8]) =
                *reinterpret_cast<uint4*>(q);
        }
    }
}

// ---------------- y proj MFMA: y = Wob @ Ob^T, Ob tile staged via LDS (coalesced) -----------
__global__ __launch_bounds__(256) void yproj_k(const unsigned short* __restrict__ Wob,
                                               const unsigned short* __restrict__ Ob,
                                               float* __restrict__ y) {
    __shared__ __align__(16) char ols[32768];   // Ob tile [32n][512c] bf16, rows 1024B, swizzled
    const int t = threadIdx.x;
    const int w = t >> 6, l = t & 63;
    const int la = l & 31, lg = l >> 5;
    const int n0 = blockIdx.x * 32;

#pragma unroll
    for (int i = 0; i < 8; ++i) {
        int c = i * 256 + t;
        int n = c >> 6, ch = (c & 63) * 16;
        uint4 v = *reinterpret_cast<const uint4*>(
            reinterpret_cast<const char*>(Ob + (size_t)(n0 + n) * INNER) + ch);
        *reinterpret_cast<uint4*>(ols + n * 1024 + (ch ^ ((n & 7) << 4))) = v;
    }
    __syncthreads();

    const int row = w * 32 + la;
    const int osw = (la & 7) << 4;
    f32x16 acc = {0,0,0,0,0,0,0,0,0,0,0,0,0,0,0,0};
#pragma unroll 8
    for (int ks = 0; ks < 32; ++ks) {
        bf16x8 bo = *reinterpret_cast<const bf16x8*>(
            ols + la * 1024 + ((ks * 32 + lg * 16) ^ osw));
        bf16x8 aw = *reinterpret_cast<const bf16x8*>(Wob + (size_t)row * INNER + ks * 16 + lg * 8);
        acc = __builtin_amdgcn_mfma_f32_32x32x16_bf16(aw, bo, acc, 0, 0, 0);
    }
    const int n = n0 + la;
#pragma unroll
    for (int rr = 0; rr < 4; ++rr)
#pragma unroll
        for (int q = 0; q < 4; ++q) {
            int o = w * 32 + 4 * lg + rr * 8 + q;
            y[(size_t)o * N_TOK + n] = acc[rr * 4 + q];
        }
}

extern "C" void kernel_launch(void* const* d_in, const int* in_sizes, int n_in,
                              void* d_out, int out_size, void* d_ws, size_t ws_size,
                              hipStream_t stream) {
    const float* x   = (const float*)d_in[0];
    const float* ctx = (const float*)d_in[1];
    const float* Wq  = (const float*)d_in[2];
    const float* Wk  = (const float*)d_in[3];
    const float* Wv  = (const float*)d_in[4];
    const float* Wo  = (const float*)d_in[5];
    float* y = (float*)d_out;

    char* W = (char*)d_ws;
    float* ctxp         = (float*)(W);                              // 1 MB
    unsigned short* Kb  = (unsigned short*)(W + 1u  * (1 << 20));   // 2 MB
    unsigned short* Vb  = (unsigned short*)(W + 3u  * (1 << 20));   // 2 MB
    unsigned short* xb  = (unsigned short*)(W + 5u  * (1 << 20));   // 4 MB
    unsigned short* Wqb = (unsigned short*)(W + 9u  * (1 << 20));   // 128 KB
    unsigned short* Wob = (unsigned short*)(W + 9u  * (1 << 20) + (256 << 10)); // 128 KB
    unsigned short* Qb  = (unsigned short*)(W + 10u * (1 << 20));   // 16 MB
    unsigned short* Ob  = (unsigned short*)(W + 26u * (1 << 20));   // 16 MB

    prep_k<<<dim3(64 + 1024 + 256), 256, 0, stream>>>(Wq, Wo, ctx, x, Wqb, Wob, ctxp, xb);
    projs_k<<<dim3(1024 + N_TOK / 32), 256, 0, stream>>>(ctxp, Wk, Wv, Wqb, xb, Kb, Vb, Qb);
    attn_k<<<dim3(N_TOK / 256 * NHEADS), 512, 0, stream>>>(Qb, Kb, Vb, Ob);
    yproj_k<<<dim3(N_TOK / 32), 256, 0, stream>>>(Wob, Ob, y);
}

// Round 20
// 126.046 us; speedup vs baseline: 1.0138x; 1.0138x over previous
//
#include <hip/hip_runtime.h>

#define N_TOK 16384
#define M_TOK 2048
#define NHEADS 8
#define DH 64
#define CIN 128
#define INNER 512

typedef __attribute__((ext_vector_type(8))) short bf16x8;
typedef __attribute__((ext_vector_type(16))) float f32x16;
typedef __attribute__((ext_vector_type(4))) unsigned int u32x4;
typedef __attribute__((ext_vector_type(2))) unsigned int u32x2;

// Softmax base: native exp2 (compiler-managed TRANS hazards); QS folds 0.125*log2(e)
// into Wqb so exp2(S) == exp(S/8). Single #if keeps base and scale consistent.
#if __has_builtin(__builtin_amdgcn_exp2f)
#define QS 0.18033688011112042f
#define EXPF(x) __builtin_amdgcn_exp2f(x)
#else
#define QS 0.125f
#define EXPF(x) __expf(x)
#endif

__device__ __forceinline__ unsigned short f2bf(float f) {
    unsigned u = __float_as_uint(f);
    u += 0x7fff + ((u >> 16) & 1);          // RNE
    return (unsigned short)(u >> 16);
}

__device__ __forceinline__ unsigned cvtpk(float lo, float hi) {
    unsigned r;
    asm("v_cvt_pk_bf16_f32 %0, %1, %2" : "=v"(r) : "v"(lo), "v"(hi));
    return r;
}

__device__ __forceinline__ bf16x8 mk_bf16x8(unsigned a, unsigned b, unsigned c, unsigned d) {
    union { u32x4 w; bf16x8 h; } u;
    u.w = (u32x4){a, b, c, d};
    return u.h;
}

__device__ __forceinline__ void gload16(const void* g, void* l) {
    __builtin_amdgcn_global_load_lds(
        (const __attribute__((address_space(1))) unsigned int*)g,
        (__attribute__((address_space(3))) unsigned int*)l, 16, 0, 0);
}

// ---------------- prep: wconv (0..63) + avg-pool (64..1087) + xT (1088..1343) ----------------
__global__ __launch_bounds__(256) void prep_k(const float* __restrict__ Wq,
                                              const float* __restrict__ Wo,
                                              const float* __restrict__ cin,
                                              const float* __restrict__ x,
                                              unsigned short* __restrict__ Wqb,
                                              unsigned short* __restrict__ Wob,
                                              float* __restrict__ cout,
                                              unsigned short* __restrict__ xb) {
    __shared__ unsigned short tile[64 * 132];
    const int t = threadIdx.x;
    if (blockIdx.x < 64) {
        int i = (blockIdx.x * 256 + t) * 8;
        const float* src; unsigned short* dst; float sc;
        if (i < 65536) { src = Wq + i; dst = Wqb + i; sc = QS; }
        else           { src = Wo + (i - 65536); dst = Wob + (i - 65536); sc = 1.0f; }
        float4 a = *reinterpret_cast<const float4*>(src);
        float4 b = *reinterpret_cast<const float4*>(src + 4);
        unsigned short u[8] = { f2bf(a.x * sc), f2bf(a.y * sc), f2bf(a.z * sc), f2bf(a.w * sc),
                                f2bf(b.x * sc), f2bf(b.y * sc), f2bf(b.z * sc), f2bf(b.w * sc) };
        *reinterpret_cast<uint4*>(dst) = *reinterpret_cast<uint4*>(u);
    } else if (blockIdx.x < 1088) {
        int idx = (blockIdx.x - 64) * 256 + t;
        int c = idx >> 11, m = idx & 2047;
        int d2 = m >> 8, h2 = (m >> 4) & 15, w2 = m & 15;
        const float* b = cin + c * 16384 + d2 * 2048 + h2 * 64 + w2 * 2;
        float s = b[0] + b[1] + b[32] + b[33] + b[1024] + b[1025] + b[1056] + b[1057];
        cout[idx] = s * 0.125f;
    } else {
        const int xbid = blockIdx.x - 1088;
        const int n0 = (xbid & 127) * 128;
        const int cb = (xbid >> 7) * 64;
#pragma unroll
        for (int cc2 = 0; cc2 < 2; ++cc2)
#pragma unroll
            for (int lp = 0; lp < 4; ++lp) {
                int id = lp * 256 + t;
                int row = id >> 5, ch = id & 31;
                float4 v = *reinterpret_cast<const float4*>(
                    &x[(size_t)(cb + cc2 * 32 + row) * N_TOK + n0 + ch * 4]);
                unsigned short u[4] = { f2bf(v.x), f2bf(v.y), f2bf(v.z), f2bf(v.w) };
                *reinterpret_cast<uint2*>(&tile[(cc2 * 32 + row) * 132 + ch * 4]) =
                    *reinterpret_cast<uint2*>(u);
            }
        __syncthreads();
#pragma unroll
        for (int lp = 0; lp < 4; ++lp) {
            int id = lp * 256 + t;
            int n = id >> 3, cg = id & 7;
            unsigned short u[8];
#pragma unroll
            for (int j = 0; j < 8; ++j) u[j] = tile[(cg * 8 + j) * 132 + n];
            *reinterpret_cast<uint4*>(&xb[(size_t)(n0 + n) * 128 + cb + cg * 8]) =
                *reinterpret_cast<uint4*>(u);
        }
    }
}

// ---------------- fused projections: kvproj (blocks 0..1023) + qproj (1024..1535) ----------------
__global__ __launch_bounds__(256) void projs_k(const float* __restrict__ ctx,
                                               const float* __restrict__ Wk,
                                               const float* __restrict__ Wv,
                                               const unsigned short* __restrict__ Wqb,
                                               const unsigned short* __restrict__ xb,
                                               unsigned short* __restrict__ Kb,
                                               unsigned short* __restrict__ Vb,
                                               unsigned short* __restrict__ Qb) {
    __shared__ __align__(16) char xls[8192];   // qproj: xb tile [32n][128c] bf16 swizzled
    const int b = blockIdx.x;
    const int t = threadIdx.x;
    if (b < 1024) {
        // ---- K/V proj (fp32 scalar) ----
        const int bx = b & 3, by = (b >> 2) & 127, bz = b >> 9;
        const int m0 = (bx * 256 + t) * 2;
        const int o0 = by * 4;
        const float* W = bz ? Wv : Wk;
        float acc[4][2];
#pragma unroll
        for (int j = 0; j < 4; ++j) { acc[j][0] = 0.f; acc[j][1] = 0.f; }
        for (int c4 = 0; c4 < CIN / 4; ++c4) {
            float xa[4][2];
#pragma unroll
            for (int cc = 0; cc < 4; ++cc)
                *reinterpret_cast<float2*>(xa[cc]) =
                    *reinterpret_cast<const float2*>(&ctx[(size_t)(c4 * 4 + cc) * M_TOK + m0]);
#pragma unroll
            for (int j = 0; j < 4; ++j) {
                float4 wv = *reinterpret_cast<const float4*>(&W[(o0 + j) * CIN + c4 * 4]);
#pragma unroll
                for (int k = 0; k < 2; ++k) {
                    acc[j][k] = fmaf(wv.x, xa[0][k], acc[j][k]);
                    acc[j][k] = fmaf(wv.y, xa[1][k], acc[j][k]);
                    acc[j][k] = fmaf(wv.z, xa[2][k], acc[j][k]);
                    acc[j][k] = fmaf(wv.w, xa[3][k], acc[j][k]);
                }
            }
        }
        if (bz) {
#pragma unroll
            for (int j = 0; j < 4; ++j) {
                unsigned w0 = (unsigned)f2bf(acc[j][0]) | ((unsigned)f2bf(acc[j][1]) << 16);
                *reinterpret_cast<unsigned*>(&Vb[(size_t)(o0 + j) * M_TOK + m0]) = w0;
            }
        } else {
            const int h = o0 >> 6, d0 = o0 & 63;
#pragma unroll
            for (int k = 0; k < 2; ++k) {
                unsigned short u[4];
#pragma unroll
                for (int j = 0; j < 4; ++j) u[j] = f2bf(acc[j][k]);
                *reinterpret_cast<uint2*>(&Kb[((size_t)h * M_TOK + m0 + k) * DH + d0]) =
                    *reinterpret_cast<uint2*>(u);
            }
        }
    } else {
        // ---- Q proj MFMA, xb tile staged through LDS (coalesced + swizzled) ----
        const int bid = b - 1024;
        const int w = t >> 6, l = t & 63;
        const int la = l & 31, lg = l >> 5;
        const int n0t = bid * 32;

        // stage xb[n0t..n0t+31][0..127] bf16: 512 chunks x 16B; row = 256B
#pragma unroll
        for (int i = 0; i < 2; ++i) {
            int c = i * 256 + t;
            int n = c >> 4, ch = (c & 15) * 16;
            uint4 v = *reinterpret_cast<const uint4*>(
                reinterpret_cast<const char*>(xb + (size_t)(n0t + n) * CIN) + ch);
            *reinterpret_cast<uint4*>(xls + n * 256 + (ch ^ ((n & 7) << 4))) = v;
        }
        __syncthreads();

        bf16x8 bx[8];
        const int xsw = (la & 7) << 4;
#pragma unroll
        for (int ks = 0; ks < 8; ++ks)
            bx[ks] = *reinterpret_cast<const bf16x8*>(
                xls + la * 256 + ((ks * 32 + lg * 16) ^ xsw));

        f32x16 acc[4];
#pragma unroll
        for (int os = 0; os < 4; ++os) acc[os] = (f32x16){0,0,0,0,0,0,0,0,0,0,0,0,0,0,0,0};

#pragma unroll
        for (int os = 0; os < 4; ++os) {
            const int row = w * 128 + os * 32 + la;
#pragma unroll
            for (int ks = 0; ks < 8; ++ks) {
                bf16x8 aw = *reinterpret_cast<const bf16x8*>(Wqb + (size_t)row * 128 + ks * 16 + lg * 8);
                acc[os] = __builtin_amdgcn_mfma_f32_32x32x16_bf16(aw, bx[ks], acc[os], 0, 0, 0);
            }
        }
        const int n = n0t + la;
#pragma unroll
        for (int os = 0; os < 4; ++os) {
            const int h = w * 2 + (os >> 1);
            const int dbase = (os & 1) * 32 + 4 * lg;
#pragma unroll
            for (int rr = 0; rr < 4; ++rr) {
                unsigned p0 = cvtpk(acc[os][rr * 4 + 0], acc[os][rr * 4 + 1]);
                unsigned p1 = cvtpk(acc[os][rr * 4 + 2], acc[os][rr * 4 + 3]);
                uint2 pv = make_uint2(p0, p1);
                *reinterpret_cast<uint2*>(&Qb[((size_t)h * N_TOK + n) * DH + dbase + rr * 8]) = pv;
            }
        }
    }
}

// ---------------- MFMA flash attention: 8 waves, 256 q-rows/block, m-tile 128 ----------------
// grid 512: h = bid&7 (XCD-pinned), n0 = (bid>>3)*256. 2 blocks/CU. (R14/R18-proven)
__global__ __launch_bounds__(512, 4) void attn_k(const unsigned short* __restrict__ Qb,
                                                 const unsigned short* __restrict__ Kb,
                                                 const unsigned short* __restrict__ Vb,
                                                 unsigned short* __restrict__ Ob) {
    __shared__ __align__(16) char smem[65536];   // 2 bufs x (K 16KB + V 16KB); epilogue Ot

    const int t = threadIdx.x;
    const int w = t >> 6, l = t & 63;
    const int la = l & 31, lg = l >> 5;
    const int bid = blockIdx.x;
    const int h = bid & 7;
    const int n0 = (bid >> 3) * 256;

    bf16x8 aq[4];
    {
        const unsigned short* qrow = Qb + ((size_t)h * N_TOK + n0 + w * 32 + la) * DH + lg * 8;
#pragma unroll
        for (int ks = 0; ks < 4; ++ks)
            aq[ks] = *reinterpret_cast<const bf16x8*>(qrow + ks * 16);
    }

    const bf16x8 vone = mk_bf16x8(0x3F803F80u, 0x3F803F80u, 0x3F803F80u, 0x3F803F80u);

    const char* gK = (const char*)Kb + (size_t)h * M_TOK * 128;   // K rows 128B
    const char* gV = (const char*)Vb + (size_t)h * DH * 4096;     // V rows 4096B

    // Index-based staging addresses only (loop-carried pointer chains spill: R11/R12).
    auto stage = [&](int b, int tile) {
        char* buf = smem + b * 32768;
#pragma unroll
        for (int i = 0; i < 2; ++i) {
            int c = t + i * 512;
            int row = c >> 3, o16 = (c & 7) << 4;
            gload16(gK + (size_t)(tile * 128 + row) * 128 + (o16 ^ ((row & 7) << 4)),
                    buf + c * 16);
            int vrow = c >> 4, vo16 = (c & 15) << 4;
            gload16(gV + (size_t)vrow * 4096 + tile * 256 + (vo16 ^ ((vrow & 7) << 4)),
                    buf + 16384 + c * 16);
        }
    };

    f32x16 oacc0 = {0,0,0,0,0,0,0,0,0,0,0,0,0,0,0,0};
    f32x16 oacc1 = {0,0,0,0,0,0,0,0,0,0,0,0,0,0,0,0};
    f32x16 oaccS = {0,0,0,0,0,0,0,0,0,0,0,0,0,0,0,0};   // rowsum via mfma(P, ones)

    stage(0, 0);
    __syncthreads();

#pragma unroll 2
    for (int mt = 0; mt < M_TOK / 128; ++mt) {
        const int cb = (mt & 1) * 32768;
        if (mt < M_TOK / 128 - 1) stage((mt & 1) ^ 1, mt + 1);

#pragma unroll
        for (int ms = 0; ms < 4; ++ms) {
            f32x16 sacc = {0,0,0,0,0,0,0,0,0,0,0,0,0,0,0,0};
            __builtin_amdgcn_s_setprio(1);
#pragma unroll
            for (int ks = 0; ks < 4; ++ks) {
                const int row = ms * 32 + la;
                bf16x8 ak = *reinterpret_cast<const bf16x8*>(
                    smem + cb + row * 128 + ((32 * ks + 16 * lg) ^ ((row & 7) << 4)));
                sacc = __builtin_amdgcn_mfma_f32_32x32x16_bf16(ak, aq[ks], sacc, 0, 0, 0);
            }
            __builtin_amdgcn_s_setprio(0);
            float p[16];
#pragma unroll
            for (int r = 0; r < 16; ++r) p[r] = EXPF(sacc[r]);
            u32x2 s0 = __builtin_amdgcn_permlane32_swap(cvtpk(p[0], p[1]),  cvtpk(p[4], p[5]),  false, false);
            u32x2 s1 = __builtin_amdgcn_permlane32_swap(cvtpk(p[2], p[3]),  cvtpk(p[6], p[7]),  false, false);
            u32x2 s2 = __builtin_amdgcn_permlane32_swap(cvtpk(p[8], p[9]),  cvtpk(p[12], p[13]), false, false);
            u32x2 s3 = __builtin_amdgcn_permlane32_swap(cvtpk(p[10], p[11]), cvtpk(p[14], p[15]), false, false);
            bf16x8 pa0 = mk_bf16x8(s0.x, s1.x, s0.y, s1.y);
            bf16x8 pa1 = mk_bf16x8(s2.x, s3.x, s2.y, s3.y);
            __builtin_amdgcn_s_setprio(1);
            oaccS = __builtin_amdgcn_mfma_f32_32x32x16_bf16(pa0, vone, oaccS, 0, 0, 0);
            oaccS = __builtin_amdgcn_mfma_f32_32x32x16_bf16(pa1, vone, oaccS, 0, 0, 0);
            {
                const int vrow = la, vs = (vrow & 7) << 4;
                const char* vb = smem + cb + 16384 + vrow * 256;
                bf16x8 bv0 = *reinterpret_cast<const bf16x8*>(vb + ((64 * ms + 16 * lg) ^ vs));
                bf16x8 bv1 = *reinterpret_cast<const bf16x8*>(vb + ((64 * ms + 32 + 16 * lg) ^ vs));
                oacc0 = __builtin_amdgcn_mfma_f32_32x32x16_bf16(pa0, bv0, oacc0, 0, 0, 0);
                oacc0 = __builtin_amdgcn_mfma_f32_32x32x16_bf16(pa1, bv1, oacc0, 0, 0, 0);
            }
            {
                const int vrow = 32 + la, vs = (vrow & 7) << 4;
                const char* vb = smem + cb + 16384 + vrow * 256;
                bf16x8 bv0 = *reinterpret_cast<const bf16x8*>(vb + ((64 * ms + 16 * lg) ^ vs));
                bf16x8 bv1 = *reinterpret_cast<const bf16x8*>(vb + ((64 * ms + 32 + 16 * lg) ^ vs));
                oacc1 = __builtin_amdgcn_mfma_f32_32x32x16_bf16(pa0, bv0, oacc1, 0, 0, 0);
                oacc1 = __builtin_amdgcn_mfma_f32_32x32x16_bf16(pa1, bv1, oacc1, 0, 0, 0);
            }
            __builtin_amdgcn_s_setprio(0);
        }
        __syncthreads();
    }

    float inv[16];
#pragma unroll
    for (int r = 0; r < 16; ++r) inv[r] = __builtin_amdgcn_rcpf(oaccS[r]);

    float* Ot = reinterpret_cast<float*>(smem);
#pragma unroll
    for (int pass = 0; pass < 2; ++pass) {
        __syncthreads();
        if ((w >> 2) == pass) {
            const int wl = w & 3;
#pragma unroll
            for (int dt = 0; dt < 2; ++dt)
#pragma unroll
                for (int r = 0; r < 16; r += 2) {
                    int d = dt * 32 + la;
                    int n = wl * 32 + (r & 3) + 8 * (r >> 2) + 4 * lg;
                    float2 v;
                    v.x = (dt ? oacc1[r] : oacc0[r]) * inv[r];
                    v.y = (dt ? oacc1[r + 1] : oacc0[r + 1]) * inv[r + 1];
                    *reinterpret_cast<float2*>(&Ot[d * 132 + n]) = v;
                }
        }
        __syncthreads();
#pragma unroll
        for (int i = 0; i < 2; ++i) {
            int id = i * 512 + t;
            int n = id & 127, dg = id >> 7;
            unsigned q[4];
#pragma unroll
            for (int jj = 0; jj < 4; ++jj)
                q[jj] = cvtpk(Ot[(dg * 8 + jj * 2) * 132 + n],
                              Ot[(dg * 8 + jj * 2 + 1) * 132 + n]);
            *reinterpret_cast<uint4*>(&Ob[(size_t)(n0 + pass * 128 + n) * INNER + h * 64 + dg * 8]) =
                *reinterpret_cast<uint4*>(q);
        }
    }
}

// ---------------- y proj MFMA: y = Wob @ Ob^T, Ob tile staged via LDS (coalesced) -----------
__global__ __launch_bounds__(256) void yproj_k(const unsigned short* __restrict__ Wob,
                                               const unsigned short* __restrict__ Ob,
                                               float* __restrict__ y) {
    __shared__ __align__(16) char ols[32768];   // Ob tile [32n][512c] bf16, rows 1024B, swizzled
    const int t = threadIdx.x;
    const int w = t >> 6, l = t & 63;
    const int la = l & 31, lg = l >> 5;
    const int n0 = blockIdx.x * 32;

    // stage: 2048 chunks x 16B; consecutive lanes -> consecutive 16B of one row (coalesced)
#pragma unroll
    for (int i = 0; i < 8; ++i) {
        int c = i * 256 + t;
        int n = c >> 6, ch = (c & 63) * 16;
        uint4 v = *reinterpret_cast<const uint4*>(
            reinterpret_cast<const char*>(Ob + (size_t)(n0 + n) * INNER) + ch);
        *reinterpret_cast<uint4*>(ols + n * 1024 + (ch ^ ((n & 7) << 4))) = v;
    }
    __syncthreads();

    const int row = w * 32 + la;
    const int osw = (la & 7) << 4;
    f32x16 acc = {0,0,0,0,0,0,0,0,0,0,0,0,0,0,0,0};
#pragma unroll 8
    for (int ks = 0; ks < 32; ++ks) {
        bf16x8 bo = *reinterpret_cast<const bf16x8*>(
            ols + la * 1024 + ((ks * 32 + lg * 16) ^ osw));
        bf16x8 aw = *reinterpret_cast<const bf16x8*>(Wob + (size_t)row * INNER + ks * 16 + lg * 8);
        acc = __builtin_amdgcn_mfma_f32_32x32x16_bf16(aw, bo, acc, 0, 0, 0);
    }
    const int n = n0 + la;
#pragma unroll
    for (int rr = 0; rr < 4; ++rr)
#pragma unroll
        for (int q = 0; q < 4; ++q) {
            int o = w * 32 + 4 * lg + rr * 8 + q;
            y[(size_t)o * N_TOK + n] = acc[rr * 4 + q];
        }
}

extern "C" void kernel_launch(void* const* d_in, const int* in_sizes, int n_in,
                              void* d_out, int out_size, void* d_ws, size_t ws_size,
                              hipStream_t stream) {
    const float* x   = (const float*)d_in[0];
    const float* ctx = (const float*)d_in[1];
    const float* Wq  = (const float*)d_in[2];
    const float* Wk  = (const float*)d_in[3];
    const float* Wv  = (const float*)d_in[4];
    const float* Wo  = (const float*)d_in[5];
    float* y = (float*)d_out;

    char* W = (char*)d_ws;
    float* ctxp         = (float*)(W);                              // 1 MB
    unsigned short* Kb  = (unsigned short*)(W + 1u  * (1 << 20));   // 2 MB
    unsigned short* Vb  = (unsigned short*)(W + 3u  * (1 << 20));   // 2 MB
    unsigned short* xb  = (unsigned short*)(W + 5u  * (1 << 20));   // 4 MB
    unsigned short* Wqb = (unsigned short*)(W + 9u  * (1 << 20));   // 128 KB
    unsigned short* Wob = (unsigned short*)(W + 9u  * (1 << 20) + (256 << 10)); // 128 KB
    unsigned short* Qb  = (unsigned short*)(W + 10u * (1 << 20));   // 16 MB
    unsigned short* Ob  = (unsigned short*)(W + 26u * (1 << 20));   // 16 MB

    prep_k<<<dim3(64 + 1024 + 256), 256, 0, stream>>>(Wq, Wo, ctx, x, Wqb, Wob, ctxp, xb);
    projs_k<<<dim3(1024 + N_TOK / 32), 256, 0, stream>>>(ctxp, Wk, Wv, Wqb, xb, Kb, Vb, Qb);
    attn_k<<<dim3(N_TOK / 256 * NHEADS), 512, 0, stream>>>(Qb, Kb, Vb, Ob);
    yproj_k<<<dim3(N_TOK / 32), 256, 0, stream>>>(Wob, Ob, y);
}